// Round 3
// baseline (397.450 us; speedup 1.0000x reference)
//
#include <hip/hip_runtime.h>

// Problem constants
#define Bq 16
#define Cq 512
#define Nq 4096
#define Hq 512

// ---------------------------------------------------------------------------
// K1: single pass over x computing BOTH
//     xs_c[b,c] = sum_n x[b,c,n]   (in-register row partials + wave reduce)
//     xs_n[b,n] = sum_c x[b,c,n]   (per-thread col accumulators + atomics)
// grid: Bq*32 blocks; block (b, cc) covers 16 c-rows x all 4096 n.
// thread t owns cols {4t..4t+3} + 1024*k, k=0..3.
// ---------------------------------------------------------------------------
__global__ __launch_bounds__(256) void k1_stats(const float* __restrict__ x,
                                                float* __restrict__ xs_n,
                                                float* __restrict__ xs_c){
  int blk = blockIdx.x;
  int b  = blk >> 5;
  int cc = blk & 31;
  int c0 = cc << 4;
  int t  = threadIdx.x;
  const float4* base = (const float4*)(x + ((size_t)b*Cq + c0)*Nq);
  float4 xn[4];
  #pragma unroll
  for (int k=0;k<4;++k){ xn[k].x=0.f; xn[k].y=0.f; xn[k].z=0.f; xn[k].w=0.f; }
  float rs[16];
  #pragma unroll
  for (int r=0;r<16;++r){
    const float4* row = base + (size_t)r*(Nq/4);
    float rsum = 0.f;
    #pragma unroll
    for (int k=0;k<4;++k){
      float4 v = row[t + (k<<8)];
      xn[k].x += v.x; xn[k].y += v.y; xn[k].z += v.z; xn[k].w += v.w;
      rsum += (v.x + v.y) + (v.z + v.w);
    }
    rs[r] = rsum;
  }
  // xs_n: coalesced atomic adds (64 consecutive addresses per wave quarter)
  float* dst = xs_n + (size_t)b*Nq + t*4;
  #pragma unroll
  for (int k=0;k<4;++k){
    atomicAdd(dst + k*1024 + 0, xn[k].x);
    atomicAdd(dst + k*1024 + 1, xn[k].y);
    atomicAdd(dst + k*1024 + 2, xn[k].z);
    atomicAdd(dst + k*1024 + 3, xn[k].w);
  }
  // xs_c: reduce rs[r] over the 256 threads
  __shared__ float red[4][16];
  int wave = t >> 6;
  int lane = t & 63;
  #pragma unroll
  for (int r=0;r<16;++r){
    float v = rs[r];
    #pragma unroll
    for (int off=32; off; off>>=1) v += __shfl_down(v, off, 64);
    if (lane == 0) red[wave][r] = v;
  }
  __syncthreads();
  if (t < 16)
    xs_c[(size_t)b*Cq + c0 + t] = (red[0][t]+red[1][t])+(red[2][t]+red[3][t]);
}

// ---------------------------------------------------------------------------
// K2: s_cf[b,h] = sum_n xs_n[b,n]*w_cf[h,n]   (blocks [0,512))
//     s_sf[b,h] = sum_c xs_c[b,c]*w_sf[h,c]   (blocks [512,1024))
// ---------------------------------------------------------------------------
__global__ __launch_bounds__(256) void k2_s(const float* __restrict__ w_cf,
                                            const float* __restrict__ w_sf,
                                            const float* __restrict__ xs_n,
                                            const float* __restrict__ xs_c,
                                            float* __restrict__ s_cf,
                                            float* __restrict__ s_sf){
  __shared__ float lds[4];
  int blk = blockIdx.x;
  const float* w; const float* src; float* dst; int L;
  if (blk < Hq) { w = w_cf + (size_t)blk*Nq; src = xs_n; dst = s_cf; L = Nq; }
  else          { w = w_sf + (size_t)(blk-Hq)*Cq; src = xs_c; dst = s_sf; L = Cq; }
  int h = blk & (Hq-1);
  float acc[Bq];
  #pragma unroll
  for (int b=0;b<Bq;b++) acc[b]=0.f;
  for (int i = threadIdx.x; i < L; i += 256){
    float wv = w[i];
    #pragma unroll
    for (int b=0;b<Bq;b++) acc[b] += wv * src[b*L + i];
  }
  #pragma unroll
  for (int b=0;b<Bq;b++){
    float v = acc[b];
    #pragma unroll
    for (int off=32; off; off>>=1) v += __shfl_down(v, off, 64);
    if ((threadIdx.x & 63)==0) lds[threadIdx.x>>6] = v;
    __syncthreads();
    if (threadIdx.x==0) dst[b*Hq + h] = (lds[0]+lds[1])+(lds[2]+lds[3]);
    __syncthreads();
  }
}

// ---------------------------------------------------------------------------
// K3: v_cg[b,n] = sum_h s_cf[b,h]*w_cg[h,n]  (blocks [0,128))
//     v_sg[b,c] = sum_h s_sf[b,h]*w_sg[h,c]  (blocks [128,144))
// Atomic accumulate over h-chunks (dst pre-zeroed).
// ---------------------------------------------------------------------------
__global__ __launch_bounds__(256) void k3_v(const float* __restrict__ w_cg,
                                            const float* __restrict__ w_sg,
                                            const float* __restrict__ s_cf,
                                            const float* __restrict__ s_sf,
                                            float* __restrict__ v_cg,
                                            float* __restrict__ v_sg){
  __shared__ float sl[Bq*64];
  int blk = blockIdx.x;
  const float* w; const float* s; float* dst; int L, jc, hc;
  if (blk < 128){ w=w_cg; s=s_cf; dst=v_cg; L=Nq; jc=blk>>3; hc=blk&7; }
  else { int k=blk-128; w=w_sg; s=s_sf; dst=v_sg; L=Cq; jc=k>>3; hc=k&7; }
  int h0 = hc*64;
  for (int i = threadIdx.x; i < Bq*64; i += 256){
    int b = i >> 6, hh = i & 63;
    sl[i] = s[b*Hq + h0 + hh];
  }
  __syncthreads();
  int j = (jc<<8) + (int)threadIdx.x;
  float acc[Bq];
  #pragma unroll
  for (int b=0;b<Bq;b++) acc[b]=0.f;
  for (int hh=0; hh<64; ++hh){
    float wv = w[(size_t)(h0+hh)*L + j];
    #pragma unroll
    for (int b=0;b<Bq;b++) acc[b] += sl[b*64+hh]*wv;
  }
  #pragma unroll
  for (int b=0;b<Bq;b++) atomicAdd(&dst[b*L + j], acc[b]);
}

// ---------------------------------------------------------------------------
// K4: single pass over x computing BOTH
//     ch_comp[b,c] = sum_n x[b,c,n]*v_cg[b,n]  (weighted row partials)
//     sp_comp[b,n] = sum_c x[b,c,n]*v_sg[b,c]  (col accumulators + atomics)
// Same tiling as K1.
// ---------------------------------------------------------------------------
__global__ __launch_bounds__(256) void k4_comp(const float* __restrict__ x,
                                               const float* __restrict__ v_cg,
                                               const float* __restrict__ v_sg,
                                               float* __restrict__ sp,
                                               float* __restrict__ ch){
  int blk = blockIdx.x;
  int b  = blk >> 5;
  int cc = blk & 31;
  int c0 = cc << 4;
  int t  = threadIdx.x;
  const float4* base = (const float4*)(x + ((size_t)b*Cq + c0)*Nq);
  const float4* vgp  = (const float4*)(v_cg + (size_t)b*Nq);
  float4 vg[4];
  #pragma unroll
  for (int k=0;k<4;++k) vg[k] = vgp[t + (k<<8)];
  float4 spa[4];
  #pragma unroll
  for (int k=0;k<4;++k){ spa[k].x=0.f; spa[k].y=0.f; spa[k].z=0.f; spa[k].w=0.f; }
  float rs[16];
  #pragma unroll
  for (int r=0;r<16;++r){
    const float4* row = base + (size_t)r*(Nq/4);
    float vsr = v_sg[(size_t)b*Cq + c0 + r];   // wave-uniform broadcast
    float rsum = 0.f;
    #pragma unroll
    for (int k=0;k<4;++k){
      float4 v = row[t + (k<<8)];
      rsum += v.x*vg[k].x + v.y*vg[k].y + v.z*vg[k].z + v.w*vg[k].w;
      spa[k].x += v.x*vsr; spa[k].y += v.y*vsr;
      spa[k].z += v.z*vsr; spa[k].w += v.w*vsr;
    }
    rs[r] = rsum;
  }
  float* dst = sp + (size_t)b*Nq + t*4;
  #pragma unroll
  for (int k=0;k<4;++k){
    atomicAdd(dst + k*1024 + 0, spa[k].x);
    atomicAdd(dst + k*1024 + 1, spa[k].y);
    atomicAdd(dst + k*1024 + 2, spa[k].z);
    atomicAdd(dst + k*1024 + 3, spa[k].w);
  }
  __shared__ float red[4][16];
  int wave = t >> 6;
  int lane = t & 63;
  #pragma unroll
  for (int r=0;r<16;++r){
    float v = rs[r];
    #pragma unroll
    for (int off=32; off; off>>=1) v += __shfl_down(v, off, 64);
    if (lane == 0) red[wave][r] = v;
  }
  __syncthreads();
  if (t < 16)
    ch[(size_t)b*Cq + c0 + t] = (red[0][t]+red[1][t])+(red[2][t]+red[3][t]);
}

// ---------------------------------------------------------------------------
// K5: softmax rows. blocks [0,16): channel (L=512); [16,32): spatial (L=4096).
// Writes fp32 masks directly into the d_out tail (return order: out, cm, sm).
// ---------------------------------------------------------------------------
__global__ __launch_bounds__(256) void k5_softmax(const float* __restrict__ ch,
                                                  const float* __restrict__ sp,
                                                  float* __restrict__ out){
  __shared__ float lds[4];
  __shared__ float bcast;
  int blk = blockIdx.x;
  const float* src; float* dst; int L;
  const size_t OUT0 = (size_t)Bq*Cq*Nq;
  if (blk < Bq){ int b=blk;    src=ch+(size_t)b*Cq; dst=out+OUT0+(size_t)b*Cq; L=Cq; }
  else         { int b=blk-Bq; src=sp+(size_t)b*Nq; dst=out+OUT0+(size_t)Bq*Cq+(size_t)b*Nq; L=Nq; }
  float m = -3.4e38f;
  for (int i=threadIdx.x;i<L;i+=256) m = fmaxf(m, src[i]);
  #pragma unroll
  for (int off=32; off; off>>=1) m = fmaxf(m, __shfl_down(m, off, 64));
  if ((threadIdx.x&63)==0) lds[threadIdx.x>>6]=m;
  __syncthreads();
  if (threadIdx.x==0) bcast = fmaxf(fmaxf(lds[0],lds[1]),fmaxf(lds[2],lds[3]));
  __syncthreads();
  m = bcast;
  float ssum=0.f;
  for (int i=threadIdx.x;i<L;i+=256) ssum += __expf(src[i]-m);
  #pragma unroll
  for (int off=32; off; off>>=1) ssum += __shfl_down(ssum, off, 64);
  __syncthreads();
  if ((threadIdx.x&63)==0) lds[threadIdx.x>>6]=ssum;
  __syncthreads();
  if (threadIdx.x==0) bcast = 1.f/((lds[0]+lds[1])+(lds[2]+lds[3]));
  __syncthreads();
  float inv = bcast;
  for (int i=threadIdx.x;i<L;i+=256) dst[i] = __expf(src[i]-m)*inv;
}

// ---------------------------------------------------------------------------
// K6: out[b,c,n] = x[b,c,n] * cm[b,c] * sm[b,n]   (float4)
// ---------------------------------------------------------------------------
__global__ __launch_bounds__(256) void k6_out(const float* __restrict__ x,
                                              float* __restrict__ out){
  const size_t OUT0 = (size_t)Bq*Cq*Nq;
  const float* cm = out + OUT0;
  const float* sm = out + OUT0 + (size_t)Bq*Cq;
  int blk = blockIdx.x;
  int b = blk >> 11;
  int r = blk & 2047;
  int c = r >> 2;
  int q = r & 3;
  size_t rowoff = ((size_t)b*Cq + c)*Nq;
  int n0 = q*1024 + (int)threadIdx.x*4;
  float4 xv = *(const float4*)(x + rowoff + n0);
  float4 sv = *(const float4*)(sm + (size_t)b*Nq + n0);
  float cmv = cm[b*Cq + c];
  float4 o;
  o.x = xv.x*cmv*sv.x; o.y = xv.y*cmv*sv.y;
  o.z = xv.z*cmv*sv.z; o.w = xv.w*cmv*sv.w;
  *(float4*)(out + rowoff + n0) = o;
}

extern "C" void kernel_launch(void* const* d_in, const int* in_sizes, int n_in,
                              void* d_out, int out_size, void* d_ws, size_t ws_size,
                              hipStream_t stream){
  const float* x    = (const float*)d_in[0];
  const float* w_cf = (const float*)d_in[1];
  const float* w_cg = (const float*)d_in[2];
  const float* w_sf = (const float*)d_in[3];
  const float* w_sg = (const float*)d_in[4];
  float* out = (float*)d_out;

  float* ws   = (float*)d_ws;
  // zero-needed regions first (atomic destinations), contiguous:
  float* xs_n = ws;                    // B*N = 65536
  float* v_cg = xs_n + Bq*Nq;          // B*N = 65536
  float* v_sg = v_cg + Bq*Nq;          // B*C = 8192
  float* spc  = v_sg + Bq*Cq;          // B*N = 65536
  // plain-store regions:
  float* xs_c = spc  + Bq*Nq;          // B*C
  float* s_cf = xs_c + Bq*Cq;          // B*H
  float* s_sf = s_cf + Bq*Hq;          // B*H
  float* chc  = s_sf + Bq*Hq;          // B*C

  size_t zbytes = (size_t)(Bq*Nq + Bq*Nq + Bq*Cq + Bq*Nq) * sizeof(float);
  if (zbytes > ws_size) zbytes = ws_size;
  hipMemsetAsync(d_ws, 0, zbytes, stream);

  k1_stats  <<<Bq*32,   256, 0, stream>>>(x, xs_n, xs_c);
  k2_s      <<<2*Hq,    256, 0, stream>>>(w_cf, w_sf, xs_n, xs_c, s_cf, s_sf);
  k3_v      <<<144,     256, 0, stream>>>(w_cg, w_sg, s_cf, s_sf, v_cg, v_sg);
  k4_comp   <<<Bq*32,   256, 0, stream>>>(x, v_cg, v_sg, spc, chc);
  k5_softmax<<<2*Bq,    256, 0, stream>>>(chc, spc, out);
  k6_out    <<<Bq*Cq*4, 256, 0, stream>>>(x, out);
}

// Round 4
// 365.834 us; speedup vs baseline: 1.0864x; 1.0864x over previous
//
#include <hip/hip_runtime.h>

// Problem constants
#define Bq 16
#define Cq 512
#define Nq 4096
#define Hq 512

// ---------------------------------------------------------------------------
// K1 (fused, atomic-free):
//   blocks [0,256):        xs_n[b,n] = sum_c x[b,c,n]  (column sums: block owns
//                          256-wide n-slice, loops all 512 c, direct store)
//   blocks [256,256+8192): xs_c[b,c] = sum_n x[b,c,n]  (row sums: wave reduce)
// Long-running column blocks placed first so they start at t=0.
// ---------------------------------------------------------------------------
__global__ __launch_bounds__(256) void k1_stats(const float* __restrict__ x,
                                                float* __restrict__ xs_n,
                                                float* __restrict__ xs_c){
  int blk = blockIdx.x;
  if (blk < 256){
    int b  = blk >> 4;
    int nc = blk & 15;
    int n  = (nc << 8) + (int)threadIdx.x;
    const float* p = x + (size_t)b*Cq*Nq + n;
    float acc = 0.f;
    #pragma unroll 16
    for (int c = 0; c < Cq; ++c) acc += p[(size_t)c*Nq];
    xs_n[(size_t)b*Nq + n] = acc;
  } else {
    __shared__ float lds[4];
    int blk2 = blk - 256;
    int b = blk2 >> 9;
    int c = blk2 & 511;
    const float4* row = (const float4*)(x + ((size_t)b*Cq + c)*Nq);
    float acc = 0.f;
    #pragma unroll
    for (int s = 0; s < 4; ++s){
      float4 v = row[s*256 + threadIdx.x];
      acc += (v.x + v.y) + (v.z + v.w);
    }
    #pragma unroll
    for (int off=32; off; off>>=1) acc += __shfl_down(acc, off, 64);
    if ((threadIdx.x & 63) == 0) lds[threadIdx.x >> 6] = acc;
    __syncthreads();
    if (threadIdx.x == 0) xs_c[(size_t)b*Cq + c] = (lds[0]+lds[1])+(lds[2]+lds[3]);
  }
}

// ---------------------------------------------------------------------------
// K2: s_cf[b,h] = sum_n xs_n[b,n]*w_cf[h,n]   (blocks [0,512))
//     s_sf[b,h] = sum_c xs_c[b,c]*w_sf[h,c]   (blocks [512,1024))
// ---------------------------------------------------------------------------
__global__ __launch_bounds__(256) void k2_s(const float* __restrict__ w_cf,
                                            const float* __restrict__ w_sf,
                                            const float* __restrict__ xs_n,
                                            const float* __restrict__ xs_c,
                                            float* __restrict__ s_cf,
                                            float* __restrict__ s_sf){
  __shared__ float lds[4];
  int blk = blockIdx.x;
  const float* w; const float* src; float* dst; int L;
  if (blk < Hq) { w = w_cf + (size_t)blk*Nq; src = xs_n; dst = s_cf; L = Nq; }
  else          { w = w_sf + (size_t)(blk-Hq)*Cq; src = xs_c; dst = s_sf; L = Cq; }
  int h = blk & (Hq-1);
  float acc[Bq];
  #pragma unroll
  for (int b=0;b<Bq;b++) acc[b]=0.f;
  for (int i = threadIdx.x; i < L; i += 256){
    float wv = w[i];
    #pragma unroll
    for (int b=0;b<Bq;b++) acc[b] += wv * src[b*L + i];
  }
  #pragma unroll
  for (int b=0;b<Bq;b++){
    float v = acc[b];
    #pragma unroll
    for (int off=32; off; off>>=1) v += __shfl_down(v, off, 64);
    if ((threadIdx.x & 63)==0) lds[threadIdx.x>>6] = v;
    __syncthreads();
    if (threadIdx.x==0) dst[b*Hq + h] = (lds[0]+lds[1])+(lds[2]+lds[3]);
    __syncthreads();
  }
}

// ---------------------------------------------------------------------------
// K3: PARTIAL products, plain stores (no atomics):
//   part_cg[hc][b][j] = sum_{h in chunk hc} s_cf[b,h]*w_cg[h,j]   blocks [0,128)
//   part_sg[hc][b][j] = sum_{h in chunk hc} s_sf[b,h]*w_sg[h,j]   blocks [128,144)
// ---------------------------------------------------------------------------
__global__ __launch_bounds__(256) void k3_v(const float* __restrict__ w_cg,
                                            const float* __restrict__ w_sg,
                                            const float* __restrict__ s_cf,
                                            const float* __restrict__ s_sf,
                                            float* __restrict__ part_cg,
                                            float* __restrict__ part_sg){
  __shared__ float sl[Bq*64];
  int blk = blockIdx.x;
  const float* w; const float* s; float* dst; int L, jc, hc;
  if (blk < 128){ w=w_cg; s=s_cf; dst=part_cg; L=Nq; jc=blk>>3; hc=blk&7; }
  else { int k=blk-128; w=w_sg; s=s_sf; dst=part_sg; L=Cq; jc=k>>3; hc=k&7; }
  int h0 = hc*64;
  for (int i = threadIdx.x; i < Bq*64; i += 256){
    int b = i >> 6, hh = i & 63;
    sl[i] = s[b*Hq + h0 + hh];
  }
  __syncthreads();
  int j = (jc<<8) + (int)threadIdx.x;
  float acc[Bq];
  #pragma unroll
  for (int b=0;b<Bq;b++) acc[b]=0.f;
  for (int hh=0; hh<64; ++hh){
    float wv = w[(size_t)(h0+hh)*L + j];
    #pragma unroll
    for (int b=0;b<Bq;b++) acc[b] += sl[b*64+hh]*wv;
  }
  #pragma unroll
  for (int b=0;b<Bq;b++) dst[((size_t)hc*Bq + b)*L + j] = acc[b];
}

// ---------------------------------------------------------------------------
// K3b: reduce the 8 h-chunk partials.
//   blocks [0,256):   v_cg[i] = sum_hc part_cg[hc*65536 + i]   (i = B*N linear)
//   blocks [256,288): v_sg[i] = sum_hc part_sg[hc*8192 + i]    (i = B*C linear)
// ---------------------------------------------------------------------------
__global__ __launch_bounds__(256) void k3b_red(const float* __restrict__ part_cg,
                                               const float* __restrict__ part_sg,
                                               float* __restrict__ v_cg,
                                               float* __restrict__ v_sg){
  int blk = blockIdx.x;
  if (blk < 256){
    int i = (blk << 8) + (int)threadIdx.x;
    float acc = 0.f;
    #pragma unroll
    for (int hc=0; hc<8; ++hc) acc += part_cg[(size_t)hc*(Bq*Nq) + i];
    v_cg[i] = acc;
  } else {
    int i = ((blk-256) << 8) + (int)threadIdx.x;
    float acc = 0.f;
    #pragma unroll
    for (int hc=0; hc<8; ++hc) acc += part_sg[(size_t)hc*(Bq*Cq) + i];
    v_sg[i] = acc;
  }
}

// ---------------------------------------------------------------------------
// K4 (fused, atomic-free):
//   blocks [0,256):        sp[b,n] = sum_c x[b,c,n]*v_sg[b,c]  (column, direct)
//   blocks [256,256+8192): ch[b,c] = sum_n x[b,c,n]*v_cg[b,n]  (row, reduce)
// ---------------------------------------------------------------------------
__global__ __launch_bounds__(256) void k4_comp(const float* __restrict__ x,
                                               const float* __restrict__ v_cg,
                                               const float* __restrict__ v_sg,
                                               float* __restrict__ sp,
                                               float* __restrict__ ch){
  int blk = blockIdx.x;
  if (blk < 256){
    int b  = blk >> 4;
    int nc = blk & 15;
    int n  = (nc << 8) + (int)threadIdx.x;
    const float* p  = x + (size_t)b*Cq*Nq + n;
    const float* vs = v_sg + (size_t)b*Cq;
    float acc = 0.f;
    #pragma unroll 16
    for (int c = 0; c < Cq; ++c) acc += p[(size_t)c*Nq] * vs[c];
    sp[(size_t)b*Nq + n] = acc;
  } else {
    __shared__ float lds[4];
    int blk2 = blk - 256;
    int b = blk2 >> 9;
    int c = blk2 & 511;
    const float4* row = (const float4*)(x + ((size_t)b*Cq + c)*Nq);
    const float4* vg  = (const float4*)(v_cg + (size_t)b*Nq);
    float acc = 0.f;
    #pragma unroll
    for (int s = 0; s < 4; ++s){
      float4 xv = row[s*256 + threadIdx.x];
      float4 vv = vg [s*256 + threadIdx.x];
      acc += xv.x*vv.x + xv.y*vv.y + xv.z*vv.z + xv.w*vv.w;
    }
    #pragma unroll
    for (int off=32; off; off>>=1) acc += __shfl_down(acc, off, 64);
    if ((threadIdx.x & 63) == 0) lds[threadIdx.x >> 6] = acc;
    __syncthreads();
    if (threadIdx.x == 0) ch[(size_t)b*Cq + c] = (lds[0]+lds[1])+(lds[2]+lds[3]);
  }
}

// ---------------------------------------------------------------------------
// K5: softmax rows. blocks [0,16): channel (L=512); [16,32): spatial (L=4096).
// Writes fp32 masks directly into the d_out tail (return order: out, cm, sm).
// ---------------------------------------------------------------------------
__global__ __launch_bounds__(256) void k5_softmax(const float* __restrict__ ch,
                                                  const float* __restrict__ sp,
                                                  float* __restrict__ out){
  __shared__ float lds[4];
  __shared__ float bcast;
  int blk = blockIdx.x;
  const float* src; float* dst; int L;
  const size_t OUT0 = (size_t)Bq*Cq*Nq;
  if (blk < Bq){ int b=blk;    src=ch+(size_t)b*Cq; dst=out+OUT0+(size_t)b*Cq; L=Cq; }
  else         { int b=blk-Bq; src=sp+(size_t)b*Nq; dst=out+OUT0+(size_t)Bq*Cq+(size_t)b*Nq; L=Nq; }
  float m = -3.4e38f;
  for (int i=threadIdx.x;i<L;i+=256) m = fmaxf(m, src[i]);
  #pragma unroll
  for (int off=32; off; off>>=1) m = fmaxf(m, __shfl_down(m, off, 64));
  if ((threadIdx.x&63)==0) lds[threadIdx.x>>6]=m;
  __syncthreads();
  if (threadIdx.x==0) bcast = fmaxf(fmaxf(lds[0],lds[1]),fmaxf(lds[2],lds[3]));
  __syncthreads();
  m = bcast;
  float ssum=0.f;
  for (int i=threadIdx.x;i<L;i+=256) ssum += __expf(src[i]-m);
  #pragma unroll
  for (int off=32; off; off>>=1) ssum += __shfl_down(ssum, off, 64);
  __syncthreads();
  if ((threadIdx.x&63)==0) lds[threadIdx.x>>6]=ssum;
  __syncthreads();
  if (threadIdx.x==0) bcast = 1.f/((lds[0]+lds[1])+(lds[2]+lds[3]));
  __syncthreads();
  float inv = bcast;
  for (int i=threadIdx.x;i<L;i+=256) dst[i] = __expf(src[i]-m)*inv;
}

// ---------------------------------------------------------------------------
// K6: out[b,c,n] = x[b,c,n] * cm[b,c] * sm[b,n]   (float4)
// ---------------------------------------------------------------------------
__global__ __launch_bounds__(256) void k6_out(const float* __restrict__ x,
                                              float* __restrict__ out){
  const size_t OUT0 = (size_t)Bq*Cq*Nq;
  const float* cm = out + OUT0;
  const float* sm = out + OUT0 + (size_t)Bq*Cq;
  int blk = blockIdx.x;
  int b = blk >> 11;
  int r = blk & 2047;
  int c = r >> 2;
  int q = r & 3;
  size_t rowoff = ((size_t)b*Cq + c)*Nq;
  int n0 = q*1024 + (int)threadIdx.x*4;
  float4 xv = *(const float4*)(x + rowoff + n0);
  float4 sv = *(const float4*)(sm + (size_t)b*Nq + n0);
  float cmv = cm[b*Cq + c];
  float4 o;
  o.x = xv.x*cmv*sv.x; o.y = xv.y*cmv*sv.y;
  o.z = xv.z*cmv*sv.z; o.w = xv.w*cmv*sv.w;
  *(float4*)(out + rowoff + n0) = o;
}

extern "C" void kernel_launch(void* const* d_in, const int* in_sizes, int n_in,
                              void* d_out, int out_size, void* d_ws, size_t ws_size,
                              hipStream_t stream){
  const float* x    = (const float*)d_in[0];
  const float* w_cf = (const float*)d_in[1];
  const float* w_cg = (const float*)d_in[2];
  const float* w_sf = (const float*)d_in[3];
  const float* w_sg = (const float*)d_in[4];
  float* out = (float*)d_out;

  float* ws      = (float*)d_ws;
  float* xs_n    = ws;                         // B*N   = 65536
  float* xs_c    = xs_n    + Bq*Nq;            // B*C   = 8192
  float* s_cf    = xs_c    + Bq*Cq;            // B*H   = 8192
  float* s_sf    = s_cf    + Bq*Hq;            // B*H   = 8192
  float* part_cg = s_sf    + Bq*Hq;            // 8*B*N = 524288
  float* part_sg = part_cg + 8*Bq*Nq;          // 8*B*C = 65536
  float* v_cg    = part_sg + 8*Bq*Cq;          // B*N   = 65536
  float* v_sg    = v_cg    + Bq*Nq;            // B*C   = 8192
  float* chc     = v_sg    + Bq*Cq;            // B*C   = 8192
  float* spc     = chc     + Bq*Cq;            // B*N   = 65536
  // total ~762k floats ~= 3.05 MB; every cell is plain-stored before read,
  // so no zero-init (and no atomics anywhere) -> no memset dispatch.

  k1_stats  <<<256 + Bq*Cq, 256, 0, stream>>>(x, xs_n, xs_c);
  k2_s      <<<2*Hq,        256, 0, stream>>>(w_cf, w_sf, xs_n, xs_c, s_cf, s_sf);
  k3_v      <<<144,         256, 0, stream>>>(w_cg, w_sg, s_cf, s_sf, part_cg, part_sg);
  k3b_red   <<<288,         256, 0, stream>>>(part_cg, part_sg, v_cg, v_sg);
  k4_comp   <<<256 + Bq*Cq, 256, 0, stream>>>(x, v_cg, v_sg, spc, chc);
  k5_softmax<<<2*Bq,        256, 0, stream>>>(chc, spc, out);
  k6_out    <<<Bq*Cq*4,     256, 0, stream>>>(x, out);
}

// Round 5
// 356.722 us; speedup vs baseline: 1.1142x; 1.0255x over previous
//
#include <hip/hip_runtime.h>

// Problem constants
#define Bq 16
#define Cq 512
#define Nq 4096
#define Hq 512

// ---------------------------------------------------------------------------
// K1 (fused, atomic-free):
//   blocks [0,256):  xs_n[b,n] = sum_c x[b,c,n]
//     block (b,nc) owns 256-wide n-slice; wave w covers c = w,w+4,...
//     float4 loads, unroll 8 (~32KB in flight/CU), LDS cross-wave reduce.
//   blocks [256,256+8192): xs_c[b,c] = sum_n x[b,c,n]  (row sums: wave reduce)
// ---------------------------------------------------------------------------
__global__ __launch_bounds__(256) void k1_stats(const float* __restrict__ x,
                                                float* __restrict__ xs_n,
                                                float* __restrict__ xs_c){
  __shared__ float red[4][256];
  int blk = blockIdx.x;
  if (blk < 256){
    int b    = blk >> 4;
    int nc   = blk & 15;
    int wave = threadIdx.x >> 6;
    int lane = threadIdx.x & 63;
    const float* p = x + (size_t)b*Cq*Nq + (nc << 8) + (lane << 2);
    float4 acc = {0.f,0.f,0.f,0.f};
    #pragma unroll 8
    for (int c = wave; c < Cq; c += 4){
      float4 v = *(const float4*)(p + (size_t)c*Nq);
      acc.x += v.x; acc.y += v.y; acc.z += v.z; acc.w += v.w;
    }
    *(float4*)&red[wave][lane << 2] = acc;
    __syncthreads();
    int t = threadIdx.x;
    float s = (red[0][t] + red[1][t]) + (red[2][t] + red[3][t]);
    xs_n[(size_t)b*Nq + (nc << 8) + t] = s;
  } else {
    int blk2 = blk - 256;
    int b = blk2 >> 9;
    int c = blk2 & 511;
    const float4* row = (const float4*)(x + ((size_t)b*Cq + c)*Nq);
    float acc = 0.f;
    #pragma unroll
    for (int s = 0; s < 4; ++s){
      float4 v = row[s*256 + threadIdx.x];
      acc += (v.x + v.y) + (v.z + v.w);
    }
    #pragma unroll
    for (int off=32; off; off>>=1) acc += __shfl_down(acc, off, 64);
    if ((threadIdx.x & 63) == 0) red[threadIdx.x >> 6][0] = acc;
    __syncthreads();
    if (threadIdx.x == 0)
      xs_c[(size_t)b*Cq + c] = (red[0][0]+red[1][0])+(red[2][0]+red[3][0]);
  }
}

// ---------------------------------------------------------------------------
// K2: s_cf[b,h] = sum_n xs_n[b,n]*w_cf[h,n]   (blocks [0,512))
//     s_sf[b,h] = sum_c xs_c[b,c]*w_sf[h,c]   (blocks [512,1024))
// float4-vectorized; batched epilogue reduce.
// ---------------------------------------------------------------------------
__global__ __launch_bounds__(256) void k2_s(const float* __restrict__ w_cf,
                                            const float* __restrict__ w_sf,
                                            const float* __restrict__ xs_n,
                                            const float* __restrict__ xs_c,
                                            float* __restrict__ s_cf,
                                            float* __restrict__ s_sf){
  __shared__ float red[4][Bq];
  int blk = blockIdx.x;
  const float* w; const float* src; float* dst; int L;
  if (blk < Hq) { w = w_cf + (size_t)blk*Nq; src = xs_n; dst = s_cf; L = Nq; }
  else          { w = w_sf + (size_t)(blk-Hq)*Cq; src = xs_c; dst = s_sf; L = Cq; }
  int h = blk & (Hq-1);
  int t = threadIdx.x;
  int wave = t >> 6, lane = t & 63;
  float acc[Bq];
  #pragma unroll
  for (int b=0;b<Bq;b++) acc[b]=0.f;
  for (int i0 = t*4; i0 < L; i0 += 1024){
    float4 wv = *(const float4*)(w + i0);
    #pragma unroll
    for (int b=0;b<Bq;b++){
      float4 sv = *(const float4*)(src + (size_t)b*L + i0);
      acc[b] += wv.x*sv.x + wv.y*sv.y + wv.z*sv.z + wv.w*sv.w;
    }
  }
  #pragma unroll
  for (int b=0;b<Bq;b++){
    float v = acc[b];
    #pragma unroll
    for (int off=32; off; off>>=1) v += __shfl_down(v, off, 64);
    if (lane == 0) red[wave][b] = v;
  }
  __syncthreads();
  if (t < Bq)
    dst[(size_t)t*Hq + h] = (red[0][t]+red[1][t])+(red[2][t]+red[3][t]);
}

// ---------------------------------------------------------------------------
// K3: PARTIAL products, plain stores (no atomics):
//   part_cg[hc][b][j] = sum_{h in chunk hc} s_cf[b,h]*w_cg[h,j]   blocks [0,128)
//   part_sg[hc][b][j] = sum_{h in chunk hc} s_sf[b,h]*w_sg[h,j]   blocks [128,144)
// ---------------------------------------------------------------------------
__global__ __launch_bounds__(256) void k3_v(const float* __restrict__ w_cg,
                                            const float* __restrict__ w_sg,
                                            const float* __restrict__ s_cf,
                                            const float* __restrict__ s_sf,
                                            float* __restrict__ part_cg,
                                            float* __restrict__ part_sg){
  __shared__ float sl[Bq*64];
  int blk = blockIdx.x;
  const float* w; const float* s; float* dst; int L, jc, hc;
  if (blk < 128){ w=w_cg; s=s_cf; dst=part_cg; L=Nq; jc=blk>>3; hc=blk&7; }
  else { int k=blk-128; w=w_sg; s=s_sf; dst=part_sg; L=Cq; jc=k>>3; hc=k&7; }
  int h0 = hc*64;
  for (int i = threadIdx.x; i < Bq*64; i += 256){
    int b = i >> 6, hh = i & 63;
    sl[i] = s[b*Hq + h0 + hh];
  }
  __syncthreads();
  int j = (jc<<8) + (int)threadIdx.x;
  float acc[Bq];
  #pragma unroll
  for (int b=0;b<Bq;b++) acc[b]=0.f;
  for (int hh=0; hh<64; ++hh){
    float wv = w[(size_t)(h0+hh)*L + j];
    #pragma unroll
    for (int b=0;b<Bq;b++) acc[b] += sl[b*64+hh]*wv;
  }
  #pragma unroll
  for (int b=0;b<Bq;b++) dst[((size_t)hc*Bq + b)*L + j] = acc[b];
}

// ---------------------------------------------------------------------------
// K3b: reduce the 8 h-chunk partials.
// ---------------------------------------------------------------------------
__global__ __launch_bounds__(256) void k3b_red(const float* __restrict__ part_cg,
                                               const float* __restrict__ part_sg,
                                               float* __restrict__ v_cg,
                                               float* __restrict__ v_sg){
  int blk = blockIdx.x;
  if (blk < 256){
    int i = (blk << 8) + (int)threadIdx.x;
    float acc = 0.f;
    #pragma unroll
    for (int hc=0; hc<8; ++hc) acc += part_cg[(size_t)hc*(Bq*Nq) + i];
    v_cg[i] = acc;
  } else {
    int i = ((blk-256) << 8) + (int)threadIdx.x;
    float acc = 0.f;
    #pragma unroll
    for (int hc=0; hc<8; ++hc) acc += part_sg[(size_t)hc*(Bq*Cq) + i];
    v_sg[i] = acc;
  }
}

// ---------------------------------------------------------------------------
// K4 (fused, atomic-free):
//   blocks [0,256):  sp[b,n] = sum_c x[b,c,n]*v_sg[b,c]  (column, float4,
//                    waves split over c, LDS cross-wave reduce)
//   blocks [256,256+8192): ch[b,c] = sum_n x[b,c,n]*v_cg[b,n]  (row, reduce)
// ---------------------------------------------------------------------------
__global__ __launch_bounds__(256) void k4_comp(const float* __restrict__ x,
                                               const float* __restrict__ v_cg,
                                               const float* __restrict__ v_sg,
                                               float* __restrict__ sp,
                                               float* __restrict__ ch){
  __shared__ float red[4][256];
  int blk = blockIdx.x;
  if (blk < 256){
    int b    = blk >> 4;
    int nc   = blk & 15;
    int wave = threadIdx.x >> 6;
    int lane = threadIdx.x & 63;
    const float* p  = x + (size_t)b*Cq*Nq + (nc << 8) + (lane << 2);
    const float* vs = v_sg + (size_t)b*Cq;
    float4 acc = {0.f,0.f,0.f,0.f};
    #pragma unroll 8
    for (int c = wave; c < Cq; c += 4){
      float4 v = *(const float4*)(p + (size_t)c*Nq);
      float s = vs[c];
      acc.x += v.x*s; acc.y += v.y*s; acc.z += v.z*s; acc.w += v.w*s;
    }
    *(float4*)&red[wave][lane << 2] = acc;
    __syncthreads();
    int t = threadIdx.x;
    float s = (red[0][t] + red[1][t]) + (red[2][t] + red[3][t]);
    sp[(size_t)b*Nq + (nc << 8) + t] = s;
  } else {
    int blk2 = blk - 256;
    int b = blk2 >> 9;
    int c = blk2 & 511;
    const float4* row = (const float4*)(x + ((size_t)b*Cq + c)*Nq);
    const float4* vg  = (const float4*)(v_cg + (size_t)b*Nq);
    float acc = 0.f;
    #pragma unroll
    for (int s = 0; s < 4; ++s){
      float4 xv = row[s*256 + threadIdx.x];
      float4 vv = vg [s*256 + threadIdx.x];
      acc += xv.x*vv.x + xv.y*vv.y + xv.z*vv.z + xv.w*vv.w;
    }
    #pragma unroll
    for (int off=32; off; off>>=1) acc += __shfl_down(acc, off, 64);
    if ((threadIdx.x & 63) == 0) red[threadIdx.x >> 6][0] = acc;
    __syncthreads();
    if (threadIdx.x == 0)
      ch[(size_t)b*Cq + c] = (red[0][0]+red[1][0])+(red[2][0]+red[3][0]);
  }
}

// ---------------------------------------------------------------------------
// K5: softmax rows. blocks [0,16): channel (L=512); [16,32): spatial (L=4096).
// Writes fp32 masks directly into the d_out tail (return order: out, cm, sm).
// ---------------------------------------------------------------------------
__global__ __launch_bounds__(256) void k5_softmax(const float* __restrict__ ch,
                                                  const float* __restrict__ sp,
                                                  float* __restrict__ out){
  __shared__ float lds[4];
  __shared__ float bcast;
  int blk = blockIdx.x;
  const float* src; float* dst; int L;
  const size_t OUT0 = (size_t)Bq*Cq*Nq;
  if (blk < Bq){ int b=blk;    src=ch+(size_t)b*Cq; dst=out+OUT0+(size_t)b*Cq; L=Cq; }
  else         { int b=blk-Bq; src=sp+(size_t)b*Nq; dst=out+OUT0+(size_t)Bq*Cq+(size_t)b*Nq; L=Nq; }
  float m = -3.4e38f;
  for (int i=threadIdx.x;i<L;i+=256) m = fmaxf(m, src[i]);
  #pragma unroll
  for (int off=32; off; off>>=1) m = fmaxf(m, __shfl_down(m, off, 64));
  if ((threadIdx.x&63)==0) lds[threadIdx.x>>6]=m;
  __syncthreads();
  if (threadIdx.x==0) bcast = fmaxf(fmaxf(lds[0],lds[1]),fmaxf(lds[2],lds[3]));
  __syncthreads();
  m = bcast;
  float ssum=0.f;
  for (int i=threadIdx.x;i<L;i+=256) ssum += __expf(src[i]-m);
  #pragma unroll
  for (int off=32; off; off>>=1) ssum += __shfl_down(ssum, off, 64);
  __syncthreads();
  if ((threadIdx.x&63)==0) lds[threadIdx.x>>6]=ssum;
  __syncthreads();
  if (threadIdx.x==0) bcast = 1.f/((lds[0]+lds[1])+(lds[2]+lds[3]));
  __syncthreads();
  float inv = bcast;
  for (int i=threadIdx.x;i<L;i+=256) dst[i] = __expf(src[i]-m)*inv;
}

// ---------------------------------------------------------------------------
// K6: out[b,c,n] = x[b,c,n] * cm[b,c] * sm[b,n]   (float4)
// ---------------------------------------------------------------------------
__global__ __launch_bounds__(256) void k6_out(const float* __restrict__ x,
                                              float* __restrict__ out){
  const size_t OUT0 = (size_t)Bq*Cq*Nq;
  const float* cm = out + OUT0;
  const float* sm = out + OUT0 + (size_t)Bq*Cq;
  int blk = blockIdx.x;
  int b = blk >> 11;
  int r = blk & 2047;
  int c = r >> 2;
  int q = r & 3;
  size_t rowoff = ((size_t)b*Cq + c)*Nq;
  int n0 = q*1024 + (int)threadIdx.x*4;
  float4 xv = *(const float4*)(x + rowoff + n0);
  float4 sv = *(const float4*)(sm + (size_t)b*Nq + n0);
  float cmv = cm[b*Cq + c];
  float4 o;
  o.x = xv.x*cmv*sv.x; o.y = xv.y*cmv*sv.y;
  o.z = xv.z*cmv*sv.z; o.w = xv.w*cmv*sv.w;
  *(float4*)(out + rowoff + n0) = o;
}

extern "C" void kernel_launch(void* const* d_in, const int* in_sizes, int n_in,
                              void* d_out, int out_size, void* d_ws, size_t ws_size,
                              hipStream_t stream){
  const float* x    = (const float*)d_in[0];
  const float* w_cf = (const float*)d_in[1];
  const float* w_cg = (const float*)d_in[2];
  const float* w_sf = (const float*)d_in[3];
  const float* w_sg = (const float*)d_in[4];
  float* out = (float*)d_out;

  float* ws      = (float*)d_ws;
  float* xs_n    = ws;                         // B*N
  float* xs_c    = xs_n    + Bq*Nq;            // B*C
  float* s_cf    = xs_c    + Bq*Cq;            // B*H
  float* s_sf    = s_cf    + Bq*Hq;            // B*H
  float* part_cg = s_sf    + Bq*Hq;            // 8*B*N
  float* part_sg = part_cg + 8*Bq*Nq;          // 8*B*C
  float* v_cg    = part_sg + 8*Bq*Cq;          // B*N
  float* v_sg    = v_cg    + Bq*Nq;            // B*C
  float* chc     = v_sg    + Bq*Cq;            // B*C
  float* spc     = chc     + Bq*Cq;            // B*N
  // every cell plain-stored before read; no atomics; no memset needed.

  k1_stats  <<<256 + Bq*Cq, 256, 0, stream>>>(x, xs_n, xs_c);
  k2_s      <<<2*Hq,        256, 0, stream>>>(w_cf, w_sf, xs_n, xs_c, s_cf, s_sf);
  k3_v      <<<144,         256, 0, stream>>>(w_cg, w_sg, s_cf, s_sf, part_cg, part_sg);
  k3b_red   <<<288,         256, 0, stream>>>(part_cg, part_sg, v_cg, v_sg);
  k4_comp   <<<256 + Bq*Cq, 256, 0, stream>>>(x, v_cg, v_sg, spc, chc);
  k5_softmax<<<2*Bq,        256, 0, stream>>>(chc, spc, out);
  k6_out    <<<Bq*Cq*4,     256, 0, stream>>>(x, out);
}

// Round 6
// 322.720 us; speedup vs baseline: 1.2316x; 1.1054x over previous
//
#include <hip/hip_runtime.h>

// Problem constants
#define Bq 16
#define Cq 512
#define Nq 4096
#define Hq 512

// ---------------------------------------------------------------------------
// K1 (SINGLE pass over x, atomic-free):
// grid = B*16*4 = 1024 blocks: (b, nc = 256-wide n-slice, cq = 128-c quarter).
// Wave w handles c = cq*128 + w + 4k (k=0..31), lane l owns cols 4l..4l+3.
//  - column sums -> LDS cross-wave reduce -> part_xs_n[cq][b][n] (4 partials/n)
//  - row sums    -> wave reduce            -> part_xs_c[b][nc][c] (16 partials)
// ---------------------------------------------------------------------------
__global__ __launch_bounds__(256) void k1_stats(const float* __restrict__ x,
                                                float* __restrict__ part_xs_n,
                                                float* __restrict__ part_xs_c){
  __shared__ float red[4][256];
  int blk  = blockIdx.x;
  int b    = blk >> 6;
  int nc   = (blk >> 2) & 15;
  int cq   = blk & 3;
  int wave = threadIdx.x >> 6;
  int lane = threadIdx.x & 63;
  int c0   = cq*128 + wave;
  const float* p = x + ((size_t)b*Cq + c0)*Nq + (nc << 8) + (lane << 2);
  float* pc = part_xs_c + ((size_t)(b*16 + nc) << 9) + c0;
  float4 acc = {0.f,0.f,0.f,0.f};
  #pragma unroll 8
  for (int k = 0; k < 32; ++k){
    float4 v = *(const float4*)(p + (size_t)(k*4)*Nq);
    acc.x += v.x; acc.y += v.y; acc.z += v.z; acc.w += v.w;
    float r = (v.x + v.y) + (v.z + v.w);
    #pragma unroll
    for (int off=32; off; off>>=1) r += __shfl_down(r, off, 64);
    if (lane == 0) pc[k*4] = r;
  }
  *(float4*)&red[wave][lane << 2] = acc;
  __syncthreads();
  int t = threadIdx.x;
  part_xs_n[((size_t)(cq*Bq) + b)*Nq + (nc << 8) + t] =
      (red[0][t] + red[1][t]) + (red[2][t] + red[3][t]);
}

// ---------------------------------------------------------------------------
// K1b: xs_n[b,n] = sum_cq part_xs_n ; xs_c[b,c] = sum_nc part_xs_c
// blocks [0,256): xs_n (B*N); blocks [256,288): xs_c (B*C)
// ---------------------------------------------------------------------------
__global__ __launch_bounds__(256) void k1b_red(const float* __restrict__ part_xs_n,
                                               const float* __restrict__ part_xs_c,
                                               float* __restrict__ xs_n,
                                               float* __restrict__ xs_c){
  int blk = blockIdx.x;
  if (blk < 256){
    int i = (blk << 8) + (int)threadIdx.x;          // over B*N
    float acc = 0.f;
    #pragma unroll
    for (int cq=0; cq<4; ++cq) acc += part_xs_n[(size_t)cq*(Bq*Nq) + i];
    xs_n[i] = acc;
  } else {
    int j = ((blk-256) << 8) + (int)threadIdx.x;    // over B*C
    int b = j >> 9, c = j & 511;
    float acc = 0.f;
    #pragma unroll
    for (int nc=0; nc<16; ++nc) acc += part_xs_c[((size_t)(b*16+nc) << 9) + c];
    xs_c[j] = acc;
  }
}

// ---------------------------------------------------------------------------
// K2: s_cf[b,h] = sum_n xs_n[b,n]*w_cf[h,n]   (blocks [0,512))
//     s_sf[b,h] = sum_c xs_c[b,c]*w_sf[h,c]   (blocks [512,1024))
// ---------------------------------------------------------------------------
__global__ __launch_bounds__(256) void k2_s(const float* __restrict__ w_cf,
                                            const float* __restrict__ w_sf,
                                            const float* __restrict__ xs_n,
                                            const float* __restrict__ xs_c,
                                            float* __restrict__ s_cf,
                                            float* __restrict__ s_sf){
  __shared__ float red[4][Bq];
  int blk = blockIdx.x;
  const float* w; const float* src; float* dst; int L;
  if (blk < Hq) { w = w_cf + (size_t)blk*Nq; src = xs_n; dst = s_cf; L = Nq; }
  else          { w = w_sf + (size_t)(blk-Hq)*Cq; src = xs_c; dst = s_sf; L = Cq; }
  int h = blk & (Hq-1);
  int t = threadIdx.x;
  int wave = t >> 6, lane = t & 63;
  float acc[Bq];
  #pragma unroll
  for (int b=0;b<Bq;b++) acc[b]=0.f;
  for (int i0 = t*4; i0 < L; i0 += 1024){
    float4 wv = *(const float4*)(w + i0);
    #pragma unroll
    for (int b=0;b<Bq;b++){
      float4 sv = *(const float4*)(src + (size_t)b*L + i0);
      acc[b] += wv.x*sv.x + wv.y*sv.y + wv.z*sv.z + wv.w*sv.w;
    }
  }
  #pragma unroll
  for (int b=0;b<Bq;b++){
    float v = acc[b];
    #pragma unroll
    for (int off=32; off; off>>=1) v += __shfl_down(v, off, 64);
    if (lane == 0) red[wave][b] = v;
  }
  __syncthreads();
  if (t < Bq)
    dst[(size_t)t*Hq + h] = (red[0][t]+red[1][t])+(red[2][t]+red[3][t]);
}

// ---------------------------------------------------------------------------
// K3: partial products over 64-h chunks, plain stores.
// ---------------------------------------------------------------------------
__global__ __launch_bounds__(256) void k3_v(const float* __restrict__ w_cg,
                                            const float* __restrict__ w_sg,
                                            const float* __restrict__ s_cf,
                                            const float* __restrict__ s_sf,
                                            float* __restrict__ part_cg,
                                            float* __restrict__ part_sg){
  __shared__ float sl[Bq*64];
  int blk = blockIdx.x;
  const float* w; const float* s; float* dst; int L, jc, hc;
  if (blk < 128){ w=w_cg; s=s_cf; dst=part_cg; L=Nq; jc=blk>>3; hc=blk&7; }
  else { int k=blk-128; w=w_sg; s=s_sf; dst=part_sg; L=Cq; jc=k>>3; hc=k&7; }
  int h0 = hc*64;
  for (int i = threadIdx.x; i < Bq*64; i += 256){
    int b = i >> 6, hh = i & 63;
    sl[i] = s[b*Hq + h0 + hh];
  }
  __syncthreads();
  int j = (jc<<8) + (int)threadIdx.x;
  float acc[Bq];
  #pragma unroll
  for (int b=0;b<Bq;b++) acc[b]=0.f;
  for (int hh=0; hh<64; ++hh){
    float wv = w[(size_t)(h0+hh)*L + j];
    #pragma unroll
    for (int b=0;b<Bq;b++) acc[b] += sl[b*64+hh]*wv;
  }
  #pragma unroll
  for (int b=0;b<Bq;b++) dst[((size_t)hc*Bq + b)*L + j] = acc[b];
}

// ---------------------------------------------------------------------------
// K3b: reduce the 8 h-chunk partials -> v_cg, v_sg.
// ---------------------------------------------------------------------------
__global__ __launch_bounds__(256) void k3b_red(const float* __restrict__ part_cg,
                                               const float* __restrict__ part_sg,
                                               float* __restrict__ v_cg,
                                               float* __restrict__ v_sg){
  int blk = blockIdx.x;
  if (blk < 256){
    int i = (blk << 8) + (int)threadIdx.x;
    float acc = 0.f;
    #pragma unroll
    for (int hc=0; hc<8; ++hc) acc += part_cg[(size_t)hc*(Bq*Nq) + i];
    v_cg[i] = acc;
  } else {
    int i = ((blk-256) << 8) + (int)threadIdx.x;
    float acc = 0.f;
    #pragma unroll
    for (int hc=0; hc<8; ++hc) acc += part_sg[(size_t)hc*(Bq*Cq) + i];
    v_sg[i] = acc;
  }
}

// ---------------------------------------------------------------------------
// K4 (SINGLE pass over x, atomic-free), same tiling as K1:
//  - part_sp[cq][b][n] += x*v_sg[c]   (column, LDS cross-wave reduce)
//  - part_ch[b][nc][c] = dot(x_row_slice, v_cg_slice)  (wave reduce)
// ---------------------------------------------------------------------------
__global__ __launch_bounds__(256) void k4_comp(const float* __restrict__ x,
                                               const float* __restrict__ v_cg,
                                               const float* __restrict__ v_sg,
                                               float* __restrict__ part_sp,
                                               float* __restrict__ part_ch){
  __shared__ float red[4][256];
  int blk  = blockIdx.x;
  int b    = blk >> 6;
  int nc   = (blk >> 2) & 15;
  int cq   = blk & 3;
  int wave = threadIdx.x >> 6;
  int lane = threadIdx.x & 63;
  int c0   = cq*128 + wave;
  const float* p  = x + ((size_t)b*Cq + c0)*Nq + (nc << 8) + (lane << 2);
  const float* vs = v_sg + (size_t)b*Cq + c0;
  float4 g = *(const float4*)(v_cg + (size_t)b*Nq + (nc << 8) + (lane << 2));
  float* pc = part_ch + ((size_t)(b*16 + nc) << 9) + c0;
  float4 acc = {0.f,0.f,0.f,0.f};
  #pragma unroll 8
  for (int k = 0; k < 32; ++k){
    float4 v = *(const float4*)(p + (size_t)(k*4)*Nq);
    float s = vs[k*4];
    acc.x += v.x*s; acc.y += v.y*s; acc.z += v.z*s; acc.w += v.w*s;
    float r = v.x*g.x + v.y*g.y + v.z*g.z + v.w*g.w;
    #pragma unroll
    for (int off=32; off; off>>=1) r += __shfl_down(r, off, 64);
    if (lane == 0) pc[k*4] = r;
  }
  *(float4*)&red[wave][lane << 2] = acc;
  __syncthreads();
  int t = threadIdx.x;
  part_sp[((size_t)(cq*Bq) + b)*Nq + (nc << 8) + t] =
      (red[0][t] + red[1][t]) + (red[2][t] + red[3][t]);
}

// ---------------------------------------------------------------------------
// K5: inline partial-reduce + softmax. blocks [0,16): channel (reduce 16 nc,
// L=512); [16,32): spatial (reduce 4 cq, L=4096). Masks -> d_out tail.
// ---------------------------------------------------------------------------
__global__ __launch_bounds__(256) void k5_softmax(const float* __restrict__ part_ch,
                                                  const float* __restrict__ part_sp,
                                                  float* __restrict__ out){
  __shared__ float buf[Nq];
  __shared__ float lds[4];
  __shared__ float bcast;
  int blk = blockIdx.x;
  int t = threadIdx.x;
  float* dst; int L;
  const size_t OUT0 = (size_t)Bq*Cq*Nq;
  if (blk < Bq){
    int b = blk; L = Cq;
    for (int c = t; c < Cq; c += 256){
      float s = 0.f;
      #pragma unroll
      for (int nc=0; nc<16; ++nc) s += part_ch[((size_t)(b*16+nc) << 9) + c];
      buf[c] = s;
    }
    dst = out + OUT0 + (size_t)b*Cq;
  } else {
    int b = blk - Bq; L = Nq;
    for (int n = t; n < Nq; n += 256){
      float s = 0.f;
      #pragma unroll
      for (int cq=0; cq<4; ++cq) s += part_sp[((size_t)(cq*Bq)+b)*Nq + n];
      buf[n] = s;
    }
    dst = out + OUT0 + (size_t)Bq*Cq + (size_t)b*Nq;
  }
  __syncthreads();
  float m = -3.4e38f;
  for (int i=t;i<L;i+=256) m = fmaxf(m, buf[i]);
  #pragma unroll
  for (int off=32; off; off>>=1) m = fmaxf(m, __shfl_down(m, off, 64));
  if ((t&63)==0) lds[t>>6]=m;
  __syncthreads();
  if (t==0) bcast = fmaxf(fmaxf(lds[0],lds[1]),fmaxf(lds[2],lds[3]));
  __syncthreads();
  m = bcast;
  float ssum=0.f;
  for (int i=t;i<L;i+=256) ssum += __expf(buf[i]-m);
  #pragma unroll
  for (int off=32; off; off>>=1) ssum += __shfl_down(ssum, off, 64);
  __syncthreads();
  if ((t&63)==0) lds[t>>6]=ssum;
  __syncthreads();
  if (t==0) bcast = 1.f/((lds[0]+lds[1])+(lds[2]+lds[3]));
  __syncthreads();
  float inv = bcast;
  for (int i=t;i<L;i+=256) dst[i] = __expf(buf[i]-m)*inv;
}

// ---------------------------------------------------------------------------
// K6: out[b,c,n] = x[b,c,n] * cm[b,c] * sm[b,n]   (float4)
// ---------------------------------------------------------------------------
__global__ __launch_bounds__(256) void k6_out(const float* __restrict__ x,
                                              float* __restrict__ out){
  const size_t OUT0 = (size_t)Bq*Cq*Nq;
  const float* cm = out + OUT0;
  const float* sm = out + OUT0 + (size_t)Bq*Cq;
  int blk = blockIdx.x;
  int b = blk >> 11;
  int r = blk & 2047;
  int c = r >> 2;
  int q = r & 3;
  size_t rowoff = ((size_t)b*Cq + c)*Nq;
  int n0 = q*1024 + (int)threadIdx.x*4;
  float4 xv = *(const float4*)(x + rowoff + n0);
  float4 sv = *(const float4*)(sm + (size_t)b*Nq + n0);
  float cmv = cm[b*Cq + c];
  float4 o;
  o.x = xv.x*cmv*sv.x; o.y = xv.y*cmv*sv.y;
  o.z = xv.z*cmv*sv.z; o.w = xv.w*cmv*sv.w;
  *(float4*)(out + rowoff + n0) = o;
}

extern "C" void kernel_launch(void* const* d_in, const int* in_sizes, int n_in,
                              void* d_out, int out_size, void* d_ws, size_t ws_size,
                              hipStream_t stream){
  const float* x    = (const float*)d_in[0];
  const float* w_cf = (const float*)d_in[1];
  const float* w_cg = (const float*)d_in[2];
  const float* w_sf = (const float*)d_in[3];
  const float* w_sg = (const float*)d_in[4];
  float* out = (float*)d_out;

  float* ws = (float*)d_ws;
  // persistent small buffers
  float* xs_n = ws;                  // B*N   = 65536
  float* xs_c = xs_n + Bq*Nq;        // B*C   = 8192
  float* s_cf = xs_c + Bq*Cq;        // B*H   = 8192
  float* s_sf = s_cf + Bq*Hq;        // B*H   = 8192
  float* v_cg = s_sf + Bq*Hq;        // B*N   = 65536
  float* v_sg = v_cg + Bq*Nq;        // B*C   = 8192
  // phase-reused arena (lifetimes disjoint, enforced by stream order):
  float* arena = v_sg + Bq*Cq;       // 589824 floats
  float* part_xs_n = arena;                     // 4*B*N  = 262144 (k1 -> k1b)
  float* part_xs_c = arena + 4*Bq*Nq;           // 16*B*C = 131072 (k1 -> k1b)
  float* part_cg   = arena;                     // 8*B*N  = 524288 (k3 -> k3b)
  float* part_sg   = arena + 8*Bq*Nq;           // 8*B*C  = 65536  (k3 -> k3b)
  float* part_sp   = arena;                     // 4*B*N  = 262144 (k4 -> k5)
  float* part_ch   = arena + 4*Bq*Nq;           // 16*B*C = 131072 (k4 -> k5)
  // total ws use: 163840 + 589824 floats ~= 3.0 MB; no atomics, no memset.

  k1_stats  <<<1024,    256, 0, stream>>>(x, part_xs_n, part_xs_c);
  k1b_red   <<<288,     256, 0, stream>>>(part_xs_n, part_xs_c, xs_n, xs_c);
  k2_s      <<<2*Hq,    256, 0, stream>>>(w_cf, w_sf, xs_n, xs_c, s_cf, s_sf);
  k3_v      <<<144,     256, 0, stream>>>(w_cg, w_sg, s_cf, s_sf, part_cg, part_sg);
  k3b_red   <<<288,     256, 0, stream>>>(part_cg, part_sg, v_cg, v_sg);
  k4_comp   <<<1024,    256, 0, stream>>>(x, v_cg, v_sg, part_sp, part_ch);
  k5_softmax<<<2*Bq,    256, 0, stream>>>(part_ch, part_sp, out);
  k6_out    <<<Bq*Cq*4, 256, 0, stream>>>(x, out);
}

// Round 7
// 322.241 us; speedup vs baseline: 1.2334x; 1.0015x over previous
//
#include <hip/hip_runtime.h>

// Problem constants
#define Bq 16
#define Cq 512
#define Nq 4096
#define Hq 512

// ---------------------------------------------------------------------------
// K1 (SINGLE pass over x, atomic-free):
// grid = B*16*4 = 1024 blocks: (b, nc = 256-wide n-slice, cq = 128-c quarter).
// Wave w handles c = cq*128 + w + 4k (k=0..31), lane l owns cols 4l..4l+3.
//  - column sums -> LDS cross-wave reduce -> part_xs_n[cq][b][n] (4 partials/n)
//  - row sums    -> wave reduce            -> part_xs_c[b][nc][c] (16 partials)
// ---------------------------------------------------------------------------
__global__ __launch_bounds__(256) void k1_stats(const float* __restrict__ x,
                                                float* __restrict__ part_xs_n,
                                                float* __restrict__ part_xs_c){
  __shared__ float red[4][256];
  int blk  = blockIdx.x;
  int b    = blk >> 6;
  int nc   = (blk >> 2) & 15;
  int cq   = blk & 3;
  int wave = threadIdx.x >> 6;
  int lane = threadIdx.x & 63;
  int c0   = cq*128 + wave;
  const float* p = x + ((size_t)b*Cq + c0)*Nq + (nc << 8) + (lane << 2);
  float* pc = part_xs_c + ((size_t)(b*16 + nc) << 9) + c0;
  float4 acc = {0.f,0.f,0.f,0.f};
  #pragma unroll 8
  for (int k = 0; k < 32; ++k){
    float4 v = *(const float4*)(p + (size_t)(k*4)*Nq);
    acc.x += v.x; acc.y += v.y; acc.z += v.z; acc.w += v.w;
    float r = (v.x + v.y) + (v.z + v.w);
    #pragma unroll
    for (int off=32; off; off>>=1) r += __shfl_down(r, off, 64);
    if (lane == 0) pc[k*4] = r;
  }
  *(float4*)&red[wave][lane << 2] = acc;
  __syncthreads();
  int t = threadIdx.x;
  part_xs_n[((size_t)(cq*Bq) + b)*Nq + (nc << 8) + t] =
      (red[0][t] + red[1][t]) + (red[2][t] + red[3][t]);
}

// ---------------------------------------------------------------------------
// K1b: xs_n[b,n] = sum_cq part_xs_n ; xs_c[b,c] = sum_nc part_xs_c
// blocks [0,256): xs_n (B*N); blocks [256,288): xs_c (B*C)
// ---------------------------------------------------------------------------
__global__ __launch_bounds__(256) void k1b_red(const float* __restrict__ part_xs_n,
                                               const float* __restrict__ part_xs_c,
                                               float* __restrict__ xs_n,
                                               float* __restrict__ xs_c){
  int blk = blockIdx.x;
  if (blk < 256){
    int i = (blk << 8) + (int)threadIdx.x;          // over B*N
    float acc = 0.f;
    #pragma unroll
    for (int cq=0; cq<4; ++cq) acc += part_xs_n[(size_t)cq*(Bq*Nq) + i];
    xs_n[i] = acc;
  } else {
    int j = ((blk-256) << 8) + (int)threadIdx.x;    // over B*C
    int b = j >> 9, c = j & 511;
    float acc = 0.f;
    #pragma unroll
    for (int nc=0; nc<16; ++nc) acc += part_xs_c[((size_t)(b*16+nc) << 9) + c];
    xs_c[j] = acc;
  }
}

// ---------------------------------------------------------------------------
// K2: s_cf[b,h] = sum_n xs_n[b,n]*w_cf[h,n]   (blocks [0,512))
//     s_sf[b,h] = sum_c xs_c[b,c]*w_sf[h,c]   (blocks [512,1024))
// ---------------------------------------------------------------------------
__global__ __launch_bounds__(256) void k2_s(const float* __restrict__ w_cf,
                                            const float* __restrict__ w_sf,
                                            const float* __restrict__ xs_n,
                                            const float* __restrict__ xs_c,
                                            float* __restrict__ s_cf,
                                            float* __restrict__ s_sf){
  __shared__ float red[4][Bq];
  int blk = blockIdx.x;
  const float* w; const float* src; float* dst; int L;
  if (blk < Hq) { w = w_cf + (size_t)blk*Nq; src = xs_n; dst = s_cf; L = Nq; }
  else          { w = w_sf + (size_t)(blk-Hq)*Cq; src = xs_c; dst = s_sf; L = Cq; }
  int h = blk & (Hq-1);
  int t = threadIdx.x;
  int wave = t >> 6, lane = t & 63;
  float acc[Bq];
  #pragma unroll
  for (int b=0;b<Bq;b++) acc[b]=0.f;
  for (int i0 = t*4; i0 < L; i0 += 1024){
    float4 wv = *(const float4*)(w + i0);
    #pragma unroll
    for (int b=0;b<Bq;b++){
      float4 sv = *(const float4*)(src + (size_t)b*L + i0);
      acc[b] += wv.x*sv.x + wv.y*sv.y + wv.z*sv.z + wv.w*sv.w;
    }
  }
  #pragma unroll
  for (int b=0;b<Bq;b++){
    float v = acc[b];
    #pragma unroll
    for (int off=32; off; off>>=1) v += __shfl_down(v, off, 64);
    if (lane == 0) red[wave][b] = v;
  }
  __syncthreads();
  if (t < Bq)
    dst[(size_t)t*Hq + h] = (red[0][t]+red[1][t])+(red[2][t]+red[3][t]);
}

// ---------------------------------------------------------------------------
// K3: partial products over 64-h chunks, plain stores.
//   part_cg[hc][b][j] (j over N, blocks [0,128)) ; part_sg[hc][b][j] (j over C)
// ---------------------------------------------------------------------------
__global__ __launch_bounds__(256) void k3_v(const float* __restrict__ w_cg,
                                            const float* __restrict__ w_sg,
                                            const float* __restrict__ s_cf,
                                            const float* __restrict__ s_sf,
                                            float* __restrict__ part_cg,
                                            float* __restrict__ part_sg){
  __shared__ float sl[Bq*64];
  int blk = blockIdx.x;
  const float* w; const float* s; float* dst; int L, jc, hc;
  if (blk < 128){ w=w_cg; s=s_cf; dst=part_cg; L=Nq; jc=blk>>3; hc=blk&7; }
  else { int k=blk-128; w=w_sg; s=s_sf; dst=part_sg; L=Cq; jc=k>>3; hc=k&7; }
  int h0 = hc*64;
  for (int i = threadIdx.x; i < Bq*64; i += 256){
    int b = i >> 6, hh = i & 63;
    sl[i] = s[b*Hq + h0 + hh];
  }
  __syncthreads();
  int j = (jc<<8) + (int)threadIdx.x;
  float acc[Bq];
  #pragma unroll
  for (int b=0;b<Bq;b++) acc[b]=0.f;
  for (int hh=0; hh<64; ++hh){
    float wv = w[(size_t)(h0+hh)*L + j];
    #pragma unroll
    for (int b=0;b<Bq;b++) acc[b] += sl[b*64+hh]*wv;
  }
  #pragma unroll
  for (int b=0;b<Bq;b++) dst[((size_t)hc*Bq + b)*L + j] = acc[b];
}

// ---------------------------------------------------------------------------
// K4 (SINGLE pass over x; k3b reduction INLINED — no v_cg/v_sg round trip):
// same tiling as K1. Per block:
//   vs[128] (this cq-chunk of v_sg[b,:]) = sum_hc part_sg  (LDS, coalesced)
//   g (4 floats of v_cg[b, nc-slice])    = sum_hc part_cg  (registers)
//  - part_sp[cq][b][n]  (column, LDS cross-wave reduce)
//  - part_ch[b][nc][c]  (row dot, wave reduce)
// ---------------------------------------------------------------------------
__global__ __launch_bounds__(256) void k4_comp(const float* __restrict__ x,
                                               const float* __restrict__ part_cg,
                                               const float* __restrict__ part_sg,
                                               float* __restrict__ part_sp,
                                               float* __restrict__ part_ch){
  __shared__ float red[4][256];
  __shared__ float vs[128];
  int blk  = blockIdx.x;
  int b    = blk >> 6;
  int nc   = (blk >> 2) & 15;
  int cq   = blk & 3;
  int wave = threadIdx.x >> 6;
  int lane = threadIdx.x & 63;
  int t    = threadIdx.x;
  // inline v_sg chunk: c = cq*128 + (t<128 ? t : -)
  if (t < 128){
    int c = cq*128 + t;
    float a = 0.f;
    #pragma unroll
    for (int hc=0; hc<8; ++hc) a += part_sg[((size_t)hc*Bq + b)*Cq + c];
    vs[t] = a;
  }
  // inline v_cg slice: 4 floats per thread
  int nbase = (nc << 8) + (t << 2) - ((t >> 6) << 8);  // lane<<2 within wave... use lane
  (void)nbase;
  float4 g = {0.f,0.f,0.f,0.f};
  {
    size_t off = (size_t)b*Nq + (nc << 8) + (lane << 2);
    #pragma unroll
    for (int hc=0; hc<8; ++hc){
      float4 pgv = *(const float4*)(part_cg + (size_t)hc*(Bq*Nq) + off);
      g.x += pgv.x; g.y += pgv.y; g.z += pgv.z; g.w += pgv.w;
    }
  }
  __syncthreads();
  int c0 = cq*128 + wave;
  const float* p = x + ((size_t)b*Cq + c0)*Nq + (nc << 8) + (lane << 2);
  float* pc = part_ch + ((size_t)(b*16 + nc) << 9) + c0;
  float4 acc = {0.f,0.f,0.f,0.f};
  #pragma unroll 8
  for (int k = 0; k < 32; ++k){
    float4 v = *(const float4*)(p + (size_t)(k*4)*Nq);
    float s = vs[wave + k*4];
    acc.x += v.x*s; acc.y += v.y*s; acc.z += v.z*s; acc.w += v.w*s;
    float r = v.x*g.x + v.y*g.y + v.z*g.z + v.w*g.w;
    #pragma unroll
    for (int off=32; off; off>>=1) r += __shfl_down(r, off, 64);
    if (lane == 0) pc[k*4] = r;
  }
  *(float4*)&red[wave][lane << 2] = acc;
  __syncthreads();
  part_sp[((size_t)(cq*Bq) + b)*Nq + (nc << 8) + t] =
      (red[0][t] + red[1][t]) + (red[2][t] + red[3][t]);
}

// ---------------------------------------------------------------------------
// K5: inline partial-reduce + softmax. blocks [0,16): channel (reduce 16 nc,
// L=512); [16,32): spatial (reduce 4 cq, L=4096). Masks -> d_out tail.
// ---------------------------------------------------------------------------
__global__ __launch_bounds__(256) void k5_softmax(const float* __restrict__ part_ch,
                                                  const float* __restrict__ part_sp,
                                                  float* __restrict__ out){
  __shared__ float buf[Nq];
  __shared__ float lds[4];
  __shared__ float bcast;
  int blk = blockIdx.x;
  int t = threadIdx.x;
  float* dst; int L;
  const size_t OUT0 = (size_t)Bq*Cq*Nq;
  if (blk < Bq){
    int b = blk; L = Cq;
    for (int c = t; c < Cq; c += 256){
      float s = 0.f;
      #pragma unroll
      for (int nc=0; nc<16; ++nc) s += part_ch[((size_t)(b*16+nc) << 9) + c];
      buf[c] = s;
    }
    dst = out + OUT0 + (size_t)b*Cq;
  } else {
    int b = blk - Bq; L = Nq;
    for (int n = t; n < Nq; n += 256){
      float s = 0.f;
      #pragma unroll
      for (int cq=0; cq<4; ++cq) s += part_sp[((size_t)(cq*Bq)+b)*Nq + n];
      buf[n] = s;
    }
    dst = out + OUT0 + (size_t)Bq*Cq + (size_t)b*Nq;
  }
  __syncthreads();
  float m = -3.4e38f;
  for (int i=t;i<L;i+=256) m = fmaxf(m, buf[i]);
  #pragma unroll
  for (int off=32; off; off>>=1) m = fmaxf(m, __shfl_down(m, off, 64));
  if ((t&63)==0) lds[t>>6]=m;
  __syncthreads();
  if (t==0) bcast = fmaxf(fmaxf(lds[0],lds[1]),fmaxf(lds[2],lds[3]));
  __syncthreads();
  m = bcast;
  float ssum=0.f;
  for (int i=t;i<L;i+=256) ssum += __expf(buf[i]-m);
  #pragma unroll
  for (int off=32; off; off>>=1) ssum += __shfl_down(ssum, off, 64);
  __syncthreads();
  if ((t&63)==0) lds[t>>6]=ssum;
  __syncthreads();
  if (t==0) bcast = 1.f/((lds[0]+lds[1])+(lds[2]+lds[3]));
  __syncthreads();
  float inv = bcast;
  for (int i=t;i<L;i+=256) dst[i] = __expf(buf[i]-m)*inv;
}

// ---------------------------------------------------------------------------
// K6: out[b,c,n] = x[b,c,n] * cm[b,c] * sm[b,n]   (float4)
// ---------------------------------------------------------------------------
__global__ __launch_bounds__(256) void k6_out(const float* __restrict__ x,
                                              float* __restrict__ out){
  const size_t OUT0 = (size_t)Bq*Cq*Nq;
  const float* cm = out + OUT0;
  const float* sm = out + OUT0 + (size_t)Bq*Cq;
  int blk = blockIdx.x;
  int b = blk >> 11;
  int r = blk & 2047;
  int c = r >> 2;
  int q = r & 3;
  size_t rowoff = ((size_t)b*Cq + c)*Nq;
  int n0 = q*1024 + (int)threadIdx.x*4;
  float4 xv = *(const float4*)(x + rowoff + n0);
  float4 sv = *(const float4*)(sm + (size_t)b*Nq + n0);
  float cmv = cm[b*Cq + c];
  float4 o;
  o.x = xv.x*cmv*sv.x; o.y = xv.y*cmv*sv.y;
  o.z = xv.z*cmv*sv.z; o.w = xv.w*cmv*sv.w;
  *(float4*)(out + rowoff + n0) = o;
}

extern "C" void kernel_launch(void* const* d_in, const int* in_sizes, int n_in,
                              void* d_out, int out_size, void* d_ws, size_t ws_size,
                              hipStream_t stream){
  const float* x    = (const float*)d_in[0];
  const float* w_cf = (const float*)d_in[1];
  const float* w_cg = (const float*)d_in[2];
  const float* w_sf = (const float*)d_in[3];
  const float* w_sg = (const float*)d_in[4];
  float* out = (float*)d_out;

  float* ws = (float*)d_ws;
  // persistent small buffers
  float* xs_n = ws;                  // B*N   = 65536
  float* xs_c = xs_n + Bq*Nq;        // B*C   = 8192
  float* s_cf = xs_c + Bq*Cq;        // B*H   = 8192
  float* s_sf = s_cf + Bq*Hq;        // B*H   = 8192
  // two disjoint arenas so k3's partials survive into k4 while k4 writes its own:
  float* arenaA = s_sf + Bq*Hq;                 // 589824 floats
  float* part_xs_n = arenaA;                    // 4*B*N  = 262144 (k1 -> k1b)
  float* part_xs_c = arenaA + 4*Bq*Nq;          // 16*B*C = 131072 (k1 -> k1b)
  float* part_cg   = arenaA;                    // 8*B*N  = 524288 (k3 -> k4)
  float* part_sg   = arenaA + 8*Bq*Nq;          // 8*B*C  = 65536  (k3 -> k4)
  float* arenaB = arenaA + 8*Bq*Nq + 8*Bq*Cq;   // 393216 floats
  float* part_sp   = arenaB;                    // 4*B*N  = 262144 (k4 -> k5)
  float* part_ch   = arenaB + 4*Bq*Nq;          // 16*B*C = 131072 (k4 -> k5)
  // total ws: ~4.5 MB; no atomics; no memset (every cell stored before read).

  k1_stats  <<<1024,    256, 0, stream>>>(x, part_xs_n, part_xs_c);
  k1b_red   <<<288,     256, 0, stream>>>(part_xs_n, part_xs_c, xs_n, xs_c);
  k2_s      <<<2*Hq,    256, 0, stream>>>(w_cf, w_sf, xs_n, xs_c, s_cf, s_sf);
  k3_v      <<<144,     256, 0, stream>>>(w_cg, w_sg, s_cf, s_sf, part_cg, part_sg);
  k4_comp   <<<1024,    256, 0, stream>>>(x, part_cg, part_sg, part_sp, part_ch);
  k5_softmax<<<2*Bq,    256, 0, stream>>>(part_ch, part_sp, out);
  k6_out    <<<Bq*Cq*4, 256, 0, stream>>>(x, out);
}